// Round 8
// baseline (296.674 us; speedup 1.0000x reference)
//
#include <hip/hip_runtime.h>
#include <hip/hip_fp16.h>

// Attention: ctx,W = softmax(Q K^T / 32 + mask, padmask) @ V
// B=8, QL=KL=2048, D=1024, fp32 I/O. fp16 MFMA internally (no fp32 MFMA on CDNA4).
#define B_ 8
#define QL_ 2048
#define KL_ 2048
#define D_ 1024

typedef _Float16 f16x8 __attribute__((ext_vector_type(8)));
typedef _Float16 f16x4 __attribute__((ext_vector_type(4)));
typedef float f32x4 __attribute__((ext_vector_type(4)));

// ---------------------------------------------------------------- async 16B
__device__ __forceinline__ void async16(const void* g, void* l) {
  __builtin_amdgcn_global_load_lds(
      (const __attribute__((address_space(1))) unsigned int*)g,
      (__attribute__((address_space(3))) unsigned int*)l, 16, 0, 0);
}

// ---------------------------------------------------------------- fp32->fp16
// scale folded in: Qh = (half)(Q/32) so the scores GEMM emits S' = S/sqrt(D)
// directly (also improves S' fp16 range: |S'|<~6).
__global__ __launch_bounds__(256) void cvt_k(const float* __restrict__ X,
                                             _Float16* __restrict__ Xh,
                                             float scale) {
  const int i = blockIdx.x * 256 + threadIdx.x;  // one thread per 8 floats
  const float4* src = reinterpret_cast<const float4*>(X);
  float4 a = src[i * 2], b = src[i * 2 + 1];
  f16x8 h;
  h[0] = (_Float16)(a.x * scale); h[1] = (_Float16)(a.y * scale);
  h[2] = (_Float16)(a.z * scale); h[3] = (_Float16)(a.w * scale);
  h[4] = (_Float16)(b.x * scale); h[5] = (_Float16)(b.y * scale);
  h[6] = (_Float16)(b.z * scale); h[7] = (_Float16)(b.w * scale);
  reinterpret_cast<f16x8*>(Xh)[i] = h;
}

// ---------------------------------------------------------------- V transpose
__global__ __launch_bounds__(256) void vt_k(const float* __restrict__ V,
                                            _Float16* __restrict__ VT) {
  __shared__ float tile[32][33];
  const int k0 = blockIdx.x * 32, d0 = blockIdx.y * 32, b = blockIdx.z;
  const float* Vb = V + (size_t)b * KL_ * D_;
  _Float16* VTb = VT + (size_t)b * D_ * KL_;
  const int c = threadIdx.x & 31, r = threadIdx.x >> 5;
#pragma unroll
  for (int s = 0; s < 4; ++s)
    tile[r + s * 8][c] = Vb[(size_t)(k0 + r + s * 8) * D_ + d0 + c];
  __syncthreads();
#pragma unroll
  for (int s = 0; s < 4; ++s)
    VTb[(size_t)(d0 + r + s * 8) * KL_ + k0 + c] = (_Float16)tile[c][r + s * 8];
}

// ---------------------------------------------------------------- fast GEMM
// Rounds 5-7 verified counted-vmcnt ring-5 skeleton (0 bank conflicts),
// 256x256 tile, BK=32, 512 thr = 8 waves (2M x 4N), per-wave 128x64 out.
// NEW (this round): phase-split compute (m201/T3 mechanism) — issue all 12
// ds_read_b128 (order pinned: [af mq0 x4, bfr x4] then [af mq1 x4]), then
//   s_barrier; lgkmcnt(4)  -> first 8 reads done; 16 MFMA (mq0) run while
//                             the 4 mq1 reads complete in the LDS pipe;
//   lgkmcnt(0)             -> 16 MFMA (mq1).
// DS ops complete in issue order; sched_barrier(0) pins group order and
// (rule 18) prevents MFMA hoisting past the asm waits.
// Ring ledger unchanged: top-of-iter vmcnt(12)+lgkmcnt(0)+s_barrier proves
// tile t landed everywhere and all waves' reads of t-1 are drained before
// stage(t+4) overwrites t-1's slot. Peeled vmcnt(8)/(4)/(0) tail.
// SCORES=true: S' = Qh.Kh^T stored fp16 (Nc=2048, Kc=1024);
// SCORES=false: ctx = W @ VT^T stored fp32 (Nc=1024, Kc=2048).
template <bool SCORES>
__global__ __launch_bounds__(512, 2) void fgemm_k(
    const _Float16* __restrict__ Ah, const _Float16* __restrict__ Bh,
    float* __restrict__ Cf, _Float16* __restrict__ Ch) {
  constexpr int Mc = 2048;
  constexpr int Nc = SCORES ? 2048 : 1024;
  constexpr int Kc = SCORES ? 1024 : 2048;
  constexpr int NIT = Kc / 32;
  constexpr int GX = Mc / 256, GY = Nc / 256;
  constexpr int CPX = B_ * GX * GY / 8;  // blocks per XCD chunk (exact)

  extern __shared__ char lds[];  // 5 slots x 32 KiB (A 16K + B 16K each)

  const int t = threadIdx.x;
  const int lane = t & 63;
  const int wid = t >> 6;               // 0..7
  const int wr = wid >> 2, wc = wid & 3;
  const int lo = lane & 15, hi = lane >> 4;

  // XCD-chunked swizzle (bijective: 8 | nwg): scores = 1 batch per XCD.
  const int id = blockIdx.x;
  const int swz = (id & 7) * CPX + (id >> 3);
  const int b = swz / (GX * GY);
  const int rem = swz % (GX * GY);
  const int m0 = (rem / GY) * 256, n0 = (rem % GY) * 256;

  const _Float16* Ab = Ah + (size_t)b * Mc * Kc;
  const _Float16* Bb = Bh + (size_t)b * Nc * Kc;

  // ---- staging: per wave 2 instrs/matrix, each 1 KiB = 16 rows x 64 B.
  // LDS dest wave-uniform (+lane*16 by HW); global source pre-swizzled.
  size_t aoff[2], boff[2];
  int ldst[2];
#pragma unroll
  for (int j = 0; j < 2; ++j) {
    const int row = (wid * 2 + j) * 16 + (lane >> 2);  // 0..255
    const int ch = (lane & 3) ^ ((row >> 1) & 3);      // source 16B chunk
    aoff[j] = (size_t)(m0 + row) * Kc + ch * 8;
    boff[j] = (size_t)(n0 + row) * Kc + ch * 8;
    ldst[j] = (wid * 2 + j) * 1024;  // wave-uniform byte offset
  }

  auto stage = [&](int it, int slot) {
    char* base = lds + slot * 32768;
    const int kb = it * 32;
#pragma unroll
    for (int j = 0; j < 2; ++j) {
      async16(Ab + aoff[j] + kb, base + ldst[j]);
      async16(Bb + boff[j] + kb, base + 16384 + ldst[j]);
    }
  };

  f32x4 acc[8][4];
#pragma unroll
  for (int m = 0; m < 8; ++m)
#pragma unroll
    for (int n = 0; n < 4; ++n)
#pragma unroll
      for (int i = 0; i < 4; ++i) acc[m][n][i] = 0.0f;

  // fragment LDS byte offsets (row*64 + swizzled-chunk*16)
  int raf[8], rbf_[4];
#pragma unroll
  for (int m = 0; m < 8; ++m) {
    const int r = wr * 128 + m * 16 + lo;
    raf[m] = r * 64 + ((hi ^ ((r >> 1) & 3)) << 4);
  }
#pragma unroll
  for (int n = 0; n < 4; ++n) {
    const int r = wc * 64 + n * 16 + lo;
    rbf_[n] = r * 64 + ((hi ^ ((r >> 1) & 3)) << 4);
  }

  auto compute = [&](int slot) {
    const char* Ac = lds + slot * 32768;
    const char* Bc = Ac + 16384;
    f16x8 af0[4], af1[4], bfr[4];
    // group 1 (issued first; lgkmcnt(4) below counts on this order)
#pragma unroll
    for (int m = 0; m < 4; ++m)
      af0[m] = *reinterpret_cast<const f16x8*>(Ac + raf[m]);
#pragma unroll
    for (int n = 0; n < 4; ++n)
      bfr[n] = *reinterpret_cast<const f16x8*>(Bc + rbf_[n]);
    __builtin_amdgcn_sched_barrier(0);  // pin: group 1 before group 2
    // group 2
#pragma unroll
    for (int m = 0; m < 4; ++m)
      af1[m] = *reinterpret_cast<const f16x8*>(Ac + raf[4 + m]);
    __builtin_amdgcn_s_barrier();  // phase-lock waves before MFMA clusters
    asm volatile("s_waitcnt lgkmcnt(4)" ::: "memory");  // group 1 landed
    __builtin_amdgcn_sched_barrier(0);                  // rule 18
    __builtin_amdgcn_s_setprio(1);
#pragma unroll
    for (int m = 0; m < 4; ++m)
#pragma unroll
      for (int n = 0; n < 4; ++n)
        acc[m][n] = __builtin_amdgcn_mfma_f32_16x16x32_f16(af0[m], bfr[n],
                                                           acc[m][n], 0, 0, 0);
    __builtin_amdgcn_s_setprio(0);
    asm volatile("s_waitcnt lgkmcnt(0)" ::: "memory");  // group 2 landed
    __builtin_amdgcn_sched_barrier(0);                  // rule 18
    __builtin_amdgcn_s_setprio(1);
#pragma unroll
    for (int m = 0; m < 4; ++m)
#pragma unroll
      for (int n = 0; n < 4; ++n)
        acc[4 + m][n] = __builtin_amdgcn_mfma_f32_16x16x32_f16(
            af1[m], bfr[n], acc[4 + m][n], 0, 0, 0);
    __builtin_amdgcn_s_setprio(0);
  };

  stage(0, 0);
  stage(1, 1);
  stage(2, 2);
  stage(3, 3);

  int cs = 0, ss = 4;  // compute slot, stage slot (ring of 5)
  for (int it = 0; it < NIT - 3; ++it) {
    asm volatile("s_waitcnt vmcnt(12) lgkmcnt(0)" ::: "memory");
    __builtin_amdgcn_sched_barrier(0);
    __builtin_amdgcn_s_barrier();
    if (it + 4 < NIT) {
      stage(it + 4, ss);
      if (++ss == 5) ss = 0;
    }
    compute(cs);
    if (++cs == 5) cs = 0;
  }
  asm volatile("s_waitcnt vmcnt(8) lgkmcnt(0)" ::: "memory");
  __builtin_amdgcn_sched_barrier(0);
  __builtin_amdgcn_s_barrier();
  compute(cs);
  if (++cs == 5) cs = 0;
  asm volatile("s_waitcnt vmcnt(4) lgkmcnt(0)" ::: "memory");
  __builtin_amdgcn_sched_barrier(0);
  __builtin_amdgcn_s_barrier();
  compute(cs);
  if (++cs == 5) cs = 0;
  asm volatile("s_waitcnt vmcnt(0) lgkmcnt(0)" ::: "memory");
  __builtin_amdgcn_sched_barrier(0);
  __builtin_amdgcn_s_barrier();
  compute(cs);

  // Epilogue: pure stores. C layout: col = lane&15, row = (lane>>4)*4 + i.
  if constexpr (SCORES) {
    _Float16* Cb = Ch + (size_t)b * Mc * Nc;  // S' fp16 into ctx region
#pragma unroll
    for (int n = 0; n < 4; ++n) {
      const int col = n0 + wc * 64 + n * 16 + lo;
#pragma unroll
      for (int m = 0; m < 8; ++m) {
        const int r0 = m0 + wr * 128 + m * 16 + hi * 4;
#pragma unroll
        for (int i = 0; i < 4; ++i)
          Cb[(size_t)(r0 + i) * Nc + col] = (_Float16)acc[m][n][i];
      }
    }
  } else {
    float* Cb = Cf + (size_t)b * Mc * Nc;
#pragma unroll
    for (int n = 0; n < 4; ++n) {
      const int col = n0 + wc * 64 + n * 16 + lo;
#pragma unroll
      for (int m = 0; m < 8; ++m) {
        const int r0 = m0 + wr * 128 + m * 16 + hi * 4;
#pragma unroll
        for (int i = 0; i < 4; ++i)
          Cb[(size_t)(r0 + i) * Nc + col] = acc[m][n][i];
      }
    }
  }
}

// ---------------------------------------------------------------- row softmax
// One wave per row: read S' fp16 (already scaled by 1/sqrt(D)), add attn_mask,
// pad fill -1e12, exact softmax, write W fp32 + Wh fp16. Masked -> exp == 0
// (matches jax); all-masked row -> uniform 1/2048 (matches jax).
__global__ __launch_bounds__(256) void softmax_k(
    const _Float16* __restrict__ Sh, float* __restrict__ W,
    _Float16* __restrict__ Wh, const float* __restrict__ mask,
    const int* __restrict__ pad) {
  const int row = blockIdx.x * 4 + (threadIdx.x >> 6);
  const int lane = threadIdx.x & 63;
  const int b = row >> 11, q = row & 2047;
  const f16x4* Sr = reinterpret_cast<const f16x4*>(Sh + (size_t)row * KL_);
  float4* Wr = reinterpret_cast<float4*>(W + (size_t)row * KL_);
  const float4* Mr = reinterpret_cast<const float4*>(mask + (size_t)q * KL_);
  const int4* Pr = reinterpret_cast<const int4*>(pad + (size_t)b * KL_);
  float4 v[8];
#pragma unroll
  for (int s = 0; s < 8; ++s) {
    f16x4 sv = Sr[s * 64 + lane];
    float4 mk = Mr[s * 64 + lane];
    int4 p = Pr[s * 64 + lane];
    float4 x;
    x.x = p.x ? -1e12f : (float)sv[0] + mk.x;
    x.y = p.y ? -1e12f : (float)sv[1] + mk.y;
    x.z = p.z ? -1e12f : (float)sv[2] + mk.z;
    x.w = p.w ? -1e12f : (float)sv[3] + mk.w;
    v[s] = x;
  }
  float mx = -3.402823466e38f;
#pragma unroll
  for (int s = 0; s < 8; ++s)
    mx = fmaxf(mx, fmaxf(fmaxf(v[s].x, v[s].y), fmaxf(v[s].z, v[s].w)));
#pragma unroll
  for (int off = 32; off > 0; off >>= 1) mx = fmaxf(mx, __shfl_xor(mx, off));
  float sum = 0.0f;
#pragma unroll
  for (int s = 0; s < 8; ++s) {
    v[s].x = __expf(v[s].x - mx);
    v[s].y = __expf(v[s].y - mx);
    v[s].z = __expf(v[s].z - mx);
    v[s].w = __expf(v[s].w - mx);
    sum += v[s].x + v[s].y + v[s].z + v[s].w;
  }
#pragma unroll
  for (int off = 32; off > 0; off >>= 1) sum += __shfl_xor(sum, off);
  const float inv = 1.0f / sum;
  f16x4* Whr = reinterpret_cast<f16x4*>(Wh + (size_t)row * KL_);
#pragma unroll
  for (int s = 0; s < 8; ++s) {
    float4 o;
    o.x = v[s].x * inv;
    o.y = v[s].y * inv;
    o.z = v[s].z * inv;
    o.w = v[s].w * inv;
    Wr[s * 64 + lane] = o;
    f16x4 h;
    h[0] = (_Float16)o.x;
    h[1] = (_Float16)o.y;
    h[2] = (_Float16)o.z;
    h[3] = (_Float16)o.w;
    Whr[s * 64 + lane] = h;
  }
}

// ---------------------------------------------------------------- launch
extern "C" void kernel_launch(void* const* d_in, const int* in_sizes, int n_in,
                              void* d_out, int out_size, void* d_ws,
                              size_t ws_size, hipStream_t stream) {
  const float* Q = (const float*)d_in[0];
  const float* K = (const float*)d_in[1];
  const float* V = (const float*)d_in[2];
  const float* mask = (const float*)d_in[3];
  const int* pad = (const int*)d_in[4];

  float* ctx = (float*)d_out;              // [8][2048][1024] fp32 (final)
  float* W = ctx + (size_t)B_ * QL_ * D_;  // [8][2048][2048] fp32 (final)
  // S' fp16 scratch: EXACTLY the ctx region (64 MiB). Dead until PV runs;
  // strict stream order (scores -> softmax -> PV) makes the reuse safe.
  _Float16* Sh = (_Float16*)d_out;

  const size_t MB = 1024 * 1024;
  // d_ws layout (>= 96 MiB, confirmed rounds 2-7):
  _Float16* VT = (_Float16*)d_ws;                     // [8][1024][2048] 32 MiB
  _Float16* Qh = (_Float16*)((char*)d_ws + 32 * MB);  // 32 MiB
  _Float16* Kh = (_Float16*)((char*)d_ws + 64 * MB);  // 32 MiB
  _Float16* Wh = Qh;                                  // 64 MiB, reused post-QK

  // opt-in to 160 KiB dynamic LDS (idempotent, non-stream API)
  (void)hipFuncSetAttribute((const void*)fgemm_k<true>,
                            hipFuncAttributeMaxDynamicSharedMemorySize, 163840);
  (void)hipFuncSetAttribute((const void*)fgemm_k<false>,
                            hipFuncAttributeMaxDynamicSharedMemorySize, 163840);

  cvt_k<<<dim3(B_ * QL_ * D_ / 8 / 256), 256, 0, stream>>>(Q, Qh, 0.03125f);
  cvt_k<<<dim3(B_ * KL_ * D_ / 8 / 256), 256, 0, stream>>>(K, Kh, 1.0f);
  vt_k<<<dim3(KL_ / 32, D_ / 32, B_), 256, 0, stream>>>(V, VT);
  fgemm_k<true><<<dim3(B_ * 8 * 8), 512, 163840, stream>>>(Qh, Kh, nullptr, Sh);
  softmax_k<<<dim3(B_ * QL_ / 4), 256, 0, stream>>>(Sh, W, Wh, mask, pad);
  fgemm_k<false><<<dim3(B_ * 8 * 4), 512, 163840, stream>>>(Wh, VT, ctx,
                                                            nullptr);
}